// Round 3
// baseline (85.100 us; speedup 1.0000x reference)
//
#include <hip/hip_runtime.h>
#include <hip/hip_bf16.h>
#include <math.h>

#define N_DENSE 13
#define N_SPARSE 26
#define SPARSE_DIM 100
#define N_FIELD 39               // 13 + 26
#define KDIM 16
#define N_FEATURES 2613          // 13 + 26*100
#define ROW_F (N_FIELD * KDIM)   // 624 elements per feature row of v
#define ROW_CH 78                // 16B chunks (8 bf16) per feature row
#define THREADS 256
#define ROWS_PER_BLOCK 4         // one 64-lane wave per row

// ---------------- pre-pass: fp32 -> packed bf16 ----------------
__global__ __launch_bounds__(256) void cvt_bf16(
    const float* __restrict__ v, unsigned int* __restrict__ o, int npairs)
{
    int stride = gridDim.x * blockDim.x;
    for (int i = blockIdx.x * blockDim.x + threadIdx.x; i < npairs; i += stride) {
        float2 f = reinterpret_cast<const float2*>(v)[i];
        __hip_bfloat16 a = __float2bfloat16(f.x);
        __hip_bfloat16 b = __float2bfloat16(f.y);
        unsigned int lo = *reinterpret_cast<unsigned short*>(&a);
        unsigned int hi = *reinterpret_cast<unsigned short*>(&b);
        o[i] = lo | (hi << 16);
    }
}

// uint4 = 8 bf16; element j sits in half-word j of the 128b chunk
__device__ __forceinline__ void accfma8(float a[8], const uint4 t, float xv) {
    a[0] = fmaf(xv, __uint_as_float(t.x << 16),          a[0]);
    a[1] = fmaf(xv, __uint_as_float(t.x & 0xffff0000u), a[1]);
    a[2] = fmaf(xv, __uint_as_float(t.y << 16),          a[2]);
    a[3] = fmaf(xv, __uint_as_float(t.y & 0xffff0000u), a[3]);
    a[4] = fmaf(xv, __uint_as_float(t.z << 16),          a[4]);
    a[5] = fmaf(xv, __uint_as_float(t.z & 0xffff0000u), a[5]);
    a[6] = fmaf(xv, __uint_as_float(t.w << 16),          a[6]);
    a[7] = fmaf(xv, __uint_as_float(t.w & 0xffff0000u), a[7]);
}
__device__ __forceinline__ void accadd8(float a[8], const uint4 t) {
    a[0] += __uint_as_float(t.x << 16);
    a[1] += __uint_as_float(t.x & 0xffff0000u);
    a[2] += __uint_as_float(t.y << 16);
    a[3] += __uint_as_float(t.y & 0xffff0000u);
    a[4] += __uint_as_float(t.z << 16);
    a[5] += __uint_as_float(t.z & 0xffff0000u);
    a[6] += __uint_as_float(t.w << 16);
    a[7] += __uint_as_float(t.w & 0xffff0000u);
}

// ---------------- main kernel: one wave (64 lanes) per batch row ----------------
// Row image = 78 chunks of 8 bf16. Lane l owns chunk l, and chunk 64+l if l<14.
// chunk c: field f = c>>1, k-half h = c&1 (k = 8h + j). Shuffle masks {2..32}
// preserve parity; final xor-1 merges the two k-halves.
__global__ __launch_bounds__(THREADS) void ffm_bf16w(
    const float* __restrict__ x,     // [B, 39]
    const float* __restrict__ w,     // [2613]
    const float* __restrict__ bias,  // [1]
    const uint4* __restrict__ vb,    // [2613, 78] packed bf16 rows
    float* __restrict__ out,         // [B]
    int B)
{
    __shared__ uint4 ldsDense[N_DENSE * ROW_CH];   // 16224 B
    for (int i = threadIdx.x; i < N_DENSE * ROW_CH; i += THREADS)
        ldsDense[i] = vb[i];
    __syncthreads();

    const int l = threadIdx.x & 63;
    const int row = blockIdx.x * ROWS_PER_BLOCK + (threadIdx.x >> 6);
    if (row >= B) return;

    const float* xr = x + row * (N_DENSE + N_SPARSE);

    // sparse row indices (wave-uniform x reads; keep in regs for gathers + lin)
    int nidx[N_SPARSE];
#pragma unroll
    for (int s = 0; s < N_SPARSE; ++s)
        nidx[s] = N_DENSE + s * SPARSE_DIM + (int)xr[N_DENSE + s];

    float a0[8], a1[8];
#pragma unroll
    for (int j = 0; j < 8; ++j) { a0[j] = 0.f; a1[j] = 0.f; }

    const bool tail = (l < ROW_CH - 64);   // l < 14
    float lin = bias[0];

    // ---- dense features (LDS broadcast); fold linear part, drop xd ----
#pragma unroll
    for (int j = 0; j < N_DENSE; ++j) {
        float xv = xr[j];
        lin = fmaf(xv, w[j], lin);
        accfma8(a0, ldsDense[j * ROW_CH + l], xv);
        if (tail) accfma8(a1, ldsDense[j * ROW_CH + 64 + l], xv);
    }

    // ---- sparse gathers: 2 features per group -> 4-6 loads in flight ----
#pragma unroll
    for (int s = 0; s < N_SPARSE; s += 2) {
        const uint4* b0 = vb + (size_t)nidx[s] * ROW_CH;
        const uint4* b1 = vb + (size_t)nidx[s + 1] * ROW_CH;
        uint4 u0 = b0[l];
        uint4 v0 = b1[l];
        uint4 u1, v1;
        if (tail) { u1 = b0[64 + l]; v1 = b1[64 + l]; }
        lin += w[nidx[s]] + w[nidx[s + 1]];
        accadd8(a0, u0);
        accadd8(a0, v0);
        if (tail) { accadd8(a1, u1); accadd8(a1, v1); }
    }

    // ---- reductions ----
    float s8[8], q8[8];
#pragma unroll
    for (int j = 0; j < 8; ++j) {
        s8[j] = a0[j] + a1[j];
        q8[j] = a0[j] * a0[j] + a1[j] * a1[j];
    }
#pragma unroll
    for (int m = 2; m <= 32; m <<= 1) {
#pragma unroll
        for (int j = 0; j < 8; ++j) {
            s8[j] += __shfl_xor(s8[j], m);
            q8[j] += __shfl_xor(q8[j], m);
        }
    }
    float c = 0.f;
#pragma unroll
    for (int j = 0; j < 8; ++j) c += s8[j] * s8[j] - q8[j];
    c += __shfl_xor(c, 1);   // merge the two k-halves

    float logit = lin + 0.5f * c;
    if (l == 0) out[row] = 1.f / (1.f + expf(-logit));
}

// ---------------- fp32 fallback (round-1 kernel, 16 lanes/row) ----------------
#define ROW_Q (ROW_F / 4)
__global__ __launch_bounds__(256) void ffm_fp32(
    const float* __restrict__ x, const float* __restrict__ w,
    const float* __restrict__ bias, const float* __restrict__ v,
    float* __restrict__ out, int B)
{
    __shared__ float ldsDense[N_DENSE * ROW_F];
    const float4* v4 = reinterpret_cast<const float4*>(v);
    float4* lds4 = reinterpret_cast<float4*>(ldsDense);
    for (int i = threadIdx.x; i < N_DENSE * ROW_Q; i += 256) lds4[i] = v4[i];
    __syncthreads();

    const int g = threadIdx.x >> 4, l = threadIdx.x & 15;
    const int row = blockIdx.x * 16 + g;
    if (row >= B) return;
    const float* xr = x + row * (N_DENSE + N_SPARSE);

    float4 acc[10];
#pragma unroll
    for (int i = 0; i < 10; ++i) acc[i] = make_float4(0.f, 0.f, 0.f, 0.f);
#pragma unroll
    for (int j = 0; j < N_DENSE; ++j) {
        float xv = xr[j];
        const float4* b = lds4 + j * ROW_Q;
#pragma unroll
        for (int i = 0; i < 10; ++i)
            if (i < 9 || l < 12) {
                float4 t = b[l + 16 * i];
                acc[i].x += xv * t.x; acc[i].y += xv * t.y;
                acc[i].z += xv * t.z; acc[i].w += xv * t.w;
            }
    }
    int nidx[N_SPARSE];
#pragma unroll
    for (int s = 0; s < N_SPARSE; ++s)
        nidx[s] = N_DENSE + s * SPARSE_DIM + (int)xr[N_DENSE + s];
    for (int s = 0; s < N_SPARSE; ++s) {
        const float4* b = v4 + (size_t)nidx[s] * ROW_Q;
#pragma unroll
        for (int i = 0; i < 10; ++i)
            if (i < 9 || l < 12) {
                float4 t = b[l + 16 * i];
                acc[i].x += t.x; acc[i].y += t.y; acc[i].z += t.z; acc[i].w += t.w;
            }
    }
    float4 s4 = make_float4(0,0,0,0), q4 = make_float4(0,0,0,0);
#pragma unroll
    for (int i = 0; i < 10; ++i) {
        s4.x += acc[i].x; s4.y += acc[i].y; s4.z += acc[i].z; s4.w += acc[i].w;
        q4.x += acc[i].x*acc[i].x; q4.y += acc[i].y*acc[i].y;
        q4.z += acc[i].z*acc[i].z; q4.w += acc[i].w*acc[i].w;
    }
#pragma unroll
    for (int m = 4; m <= 8; m <<= 1) {
        s4.x += __shfl_xor(s4.x,m); s4.y += __shfl_xor(s4.y,m);
        s4.z += __shfl_xor(s4.z,m); s4.w += __shfl_xor(s4.w,m);
        q4.x += __shfl_xor(q4.x,m); q4.y += __shfl_xor(q4.y,m);
        q4.z += __shfl_xor(q4.z,m); q4.w += __shfl_xor(q4.w,m);
    }
    float c = (s4.x*s4.x - q4.x) + (s4.y*s4.y - q4.y) +
              (s4.z*s4.z - q4.z) + (s4.w*s4.w - q4.w);
    c += __shfl_xor(c,1); c += __shfl_xor(c,2);
    float lin = bias[0];
#pragma unroll
    for (int j = 0; j < N_DENSE; ++j) lin += xr[j]*w[j];
#pragma unroll
    for (int s = 0; s < N_SPARSE; ++s) lin += w[nidx[s]];
    float logit = lin + 0.5f*c;
    if (l == 0) out[row] = 1.f/(1.f+expf(-logit));
}

extern "C" void kernel_launch(void* const* d_in, const int* in_sizes, int n_in,
                              void* d_out, int out_size, void* d_ws, size_t ws_size,
                              hipStream_t stream) {
    const float* x    = (const float*)d_in[0];
    const float* w    = (const float*)d_in[1];
    const float* bias = (const float*)d_in[2];
    const float* v    = (const float*)d_in[3];
    float* out = (float*)d_out;

    int B = in_sizes[0] / (N_DENSE + N_SPARSE);
    size_t need = (size_t)N_FEATURES * ROW_CH * sizeof(uint4);  // 3,261,024 B

    if (ws_size >= need) {
        int npairs = N_FEATURES * (ROW_F / 2);                  // 815,256
        cvt_bf16<<<2048, 256, 0, stream>>>(v, (unsigned int*)d_ws, npairs);
        int grid = (B + ROWS_PER_BLOCK - 1) / ROWS_PER_BLOCK;
        ffm_bf16w<<<grid, THREADS, 0, stream>>>(x, w, bias, (const uint4*)d_ws, out, B);
    } else {
        int grid = (B + 15) / 16;
        ffm_fp32<<<grid, 256, 0, stream>>>(x, w, bias, v, out, B);
    }
}

// Round 4
// 42.185 us; speedup vs baseline: 2.0173x; 2.0173x over previous
//
#include <hip/hip_runtime.h>
#include <hip/hip_bf16.h>
#include <math.h>

#define N_DENSE 13
#define N_SPARSE 26
#define SPARSE_DIM 100
#define N_FIELD 39               // 13 + 26 real fields
#define N_FIELD_P 40             // padded (field 39 = zeros)
#define KDIM 16
#define N_FEATURES 2613          // 13 + 26*100
#define ROW_F 624                // real elements per feature row (39*16)
#define ROW_DW 320               // padded dwords per row (40 fields * 8 k-pairs)
#define THREADS 256
#define ROWS_PER_BLOCK 4         // one 64-lane wave per row

// ---------------- pre-pass: fp32 -> packed bf16, padded to 40 fields --------
// out[n][d]: d<312 -> bf16pair(v[n*624+2d], v[n*624+2d+1]); d>=312 -> 0
__global__ __launch_bounds__(ROW_DW) void cvt_pad_bf16(
    const float* __restrict__ v, unsigned int* __restrict__ o)
{
    int n = blockIdx.x;
    int d = threadIdx.x;
    unsigned int r = 0u;
    if (d < ROW_F / 2) {
        float2 f = *reinterpret_cast<const float2*>(v + (size_t)n * ROW_F + 2 * d);
        __hip_bfloat16 a = __float2bfloat16(f.x);
        __hip_bfloat16 b = __float2bfloat16(f.y);
        unsigned int lo = *reinterpret_cast<unsigned short*>(&a);
        unsigned int hi = *reinterpret_cast<unsigned short*>(&b);
        r = lo | (hi << 16);
    }
    o[(size_t)n * ROW_DW + d] = r;
}

// dword t = 2 bf16 (elements 2d, 2d+1) -> float2 accumulate
__device__ __forceinline__ void upadd(float2& a, unsigned int t) {
    a.x += __uint_as_float(t << 16);
    a.y += __uint_as_float(t & 0xffff0000u);
}
__device__ __forceinline__ void upfma(float2& a, unsigned int t, float xv) {
    a.x = fmaf(xv, __uint_as_float(t << 16), a.x);
    a.y = fmaf(xv, __uint_as_float(t & 0xffff0000u), a.y);
}

// ---------------- main kernel: one wave per batch row -----------------------
// Row image: 320 dwords; dword d = (field f = d>>3, k-pair j = d&7).
// Lane l owns d = l + 64m (m=0..4): exactly 5 dwords, all with j = l&7.
// Lane-group {l, l+8, ..., l+56} covers all 40 fields once -> reduce with
// xor {8,16,32}; then c summed over the 8 j-groups with xor {1,2,4}.
__global__ __launch_bounds__(THREADS, 5) void ffm_pad(
    const float* __restrict__ x,     // [B, 39]
    const float* __restrict__ w,     // [2613]
    const float* __restrict__ bias,  // [1]
    const unsigned int* __restrict__ vb, // [2613, 320] padded bf16-pair rows
    float* __restrict__ out,         // [B]
    int B)
{
    __shared__ unsigned int ldsDense[N_DENSE * ROW_DW];   // 16640 B
    {
        const uint4* src = reinterpret_cast<const uint4*>(vb);
        uint4* dst = reinterpret_cast<uint4*>(ldsDense);
        for (int i = threadIdx.x; i < N_DENSE * ROW_DW / 4; i += THREADS)
            dst[i] = src[i];
    }
    __syncthreads();

    const int l = threadIdx.x & 63;
    const int row = blockIdx.x * ROWS_PER_BLOCK + (threadIdx.x >> 6);
    if (row >= B) return;

    const float* xr = x + row * (N_DENSE + N_SPARSE);

    int nidx[N_SPARSE];
#pragma unroll
    for (int s = 0; s < N_SPARSE; ++s)
        nidx[s] = N_DENSE + s * SPARSE_DIM + (int)xr[N_DENSE + s];

    float2 acc[5];
#pragma unroll
    for (int m = 0; m < 5; ++m) acc[m] = make_float2(0.f, 0.f);

    float lin = bias[0];

    // ---- dense features (LDS broadcast; fold linear part) ----
#pragma unroll
    for (int j = 0; j < N_DENSE; ++j) {
        float xv = xr[j];
        lin = fmaf(xv, w[j], lin);
#pragma unroll
        for (int m = 0; m < 5; ++m)
            upfma(acc[m], ldsDense[j * ROW_DW + 64 * m + l], xv);
    }

    // ---- sparse features: 2 features/iter -> 10 dword loads in flight ----
#pragma unroll
    for (int s = 0; s < N_SPARSE; s += 2) {
        const unsigned int* b0 = vb + (size_t)nidx[s] * ROW_DW + l;
        const unsigned int* b1 = vb + (size_t)nidx[s + 1] * ROW_DW + l;
        unsigned int u0 = b0[0],   v0 = b1[0];
        unsigned int u1 = b0[64],  v1 = b1[64];
        unsigned int u2 = b0[128], v2 = b1[128];
        unsigned int u3 = b0[192], v3 = b1[192];
        unsigned int u4 = b0[256], v4 = b1[256];
        lin += w[nidx[s]] + w[nidx[s + 1]];
        upadd(acc[0], u0); upadd(acc[0], v0);
        upadd(acc[1], u1); upadd(acc[1], v1);
        upadd(acc[2], u2); upadd(acc[2], v2);
        upadd(acc[3], u3); upadd(acc[3], v3);
        upadd(acc[4], u4); upadd(acc[4], v4);
    }

    // ---- reduction ----
    float sx = 0.f, sy = 0.f, qx = 0.f, qy = 0.f;
#pragma unroll
    for (int m = 0; m < 5; ++m) {
        sx += acc[m].x; sy += acc[m].y;
        qx = fmaf(acc[m].x, acc[m].x, qx);
        qy = fmaf(acc[m].y, acc[m].y, qy);
    }
#pragma unroll
    for (int mask = 8; mask <= 32; mask <<= 1) {
        sx += __shfl_xor(sx, mask);
        sy += __shfl_xor(sy, mask);
        qx += __shfl_xor(qx, mask);
        qy += __shfl_xor(qy, mask);
    }
    float c = (sx * sx - qx) + (sy * sy - qy);
    c += __shfl_xor(c, 1);
    c += __shfl_xor(c, 2);
    c += __shfl_xor(c, 4);

    float logit = lin + 0.5f * c;
    if (l == 0) out[row] = 1.f / (1.f + expf(-logit));
}

// ---------------- fp32 fallback (round-1 kernel, 16 lanes/row) --------------
#define ROW_Q (ROW_F / 4)
__global__ __launch_bounds__(256) void ffm_fp32(
    const float* __restrict__ x, const float* __restrict__ w,
    const float* __restrict__ bias, const float* __restrict__ v,
    float* __restrict__ out, int B)
{
    __shared__ float ldsDense[N_DENSE * ROW_F];
    const float4* v4 = reinterpret_cast<const float4*>(v);
    float4* lds4 = reinterpret_cast<float4*>(ldsDense);
    for (int i = threadIdx.x; i < N_DENSE * ROW_Q; i += 256) lds4[i] = v4[i];
    __syncthreads();

    const int g = threadIdx.x >> 4, l = threadIdx.x & 15;
    const int row = blockIdx.x * 16 + g;
    if (row >= B) return;
    const float* xr = x + row * (N_DENSE + N_SPARSE);

    float4 acc[10];
#pragma unroll
    for (int i = 0; i < 10; ++i) acc[i] = make_float4(0.f, 0.f, 0.f, 0.f);
#pragma unroll
    for (int j = 0; j < N_DENSE; ++j) {
        float xv = xr[j];
        const float4* b = lds4 + j * ROW_Q;
#pragma unroll
        for (int i = 0; i < 10; ++i)
            if (i < 9 || l < 12) {
                float4 t = b[l + 16 * i];
                acc[i].x += xv * t.x; acc[i].y += xv * t.y;
                acc[i].z += xv * t.z; acc[i].w += xv * t.w;
            }
    }
    int nidx[N_SPARSE];
#pragma unroll
    for (int s = 0; s < N_SPARSE; ++s)
        nidx[s] = N_DENSE + s * SPARSE_DIM + (int)xr[N_DENSE + s];
    for (int s = 0; s < N_SPARSE; ++s) {
        const float4* b = v4 + (size_t)nidx[s] * ROW_Q;
#pragma unroll
        for (int i = 0; i < 10; ++i)
            if (i < 9 || l < 12) {
                float4 t = b[l + 16 * i];
                acc[i].x += t.x; acc[i].y += t.y; acc[i].z += t.z; acc[i].w += t.w;
            }
    }
    float4 s4 = make_float4(0,0,0,0), q4 = make_float4(0,0,0,0);
#pragma unroll
    for (int i = 0; i < 10; ++i) {
        s4.x += acc[i].x; s4.y += acc[i].y; s4.z += acc[i].z; s4.w += acc[i].w;
        q4.x += acc[i].x*acc[i].x; q4.y += acc[i].y*acc[i].y;
        q4.z += acc[i].z*acc[i].z; q4.w += acc[i].w*acc[i].w;
    }
#pragma unroll
    for (int m = 4; m <= 8; m <<= 1) {
        s4.x += __shfl_xor(s4.x,m); s4.y += __shfl_xor(s4.y,m);
        s4.z += __shfl_xor(s4.z,m); s4.w += __shfl_xor(s4.w,m);
        q4.x += __shfl_xor(q4.x,m); q4.y += __shfl_xor(q4.y,m);
        q4.z += __shfl_xor(q4.z,m); q4.w += __shfl_xor(q4.w,m);
    }
    float c = (s4.x*s4.x - q4.x) + (s4.y*s4.y - q4.y) +
              (s4.z*s4.z - q4.z) + (s4.w*s4.w - q4.w);
    c += __shfl_xor(c,1); c += __shfl_xor(c,2);
    float lin = bias[0];
#pragma unroll
    for (int j = 0; j < N_DENSE; ++j) lin += xr[j]*w[j];
#pragma unroll
    for (int s = 0; s < N_SPARSE; ++s) lin += w[nidx[s]];
    float logit = lin + 0.5f*c;
    if (l == 0) out[row] = 1.f/(1.f+expf(-logit));
}

extern "C" void kernel_launch(void* const* d_in, const int* in_sizes, int n_in,
                              void* d_out, int out_size, void* d_ws, size_t ws_size,
                              hipStream_t stream) {
    const float* x    = (const float*)d_in[0];
    const float* w    = (const float*)d_in[1];
    const float* bias = (const float*)d_in[2];
    const float* v    = (const float*)d_in[3];
    float* out = (float*)d_out;

    int B = in_sizes[0] / (N_DENSE + N_SPARSE);
    size_t need = (size_t)N_FEATURES * ROW_DW * sizeof(unsigned int);  // 3,344,640 B

    if (ws_size >= need) {
        cvt_pad_bf16<<<N_FEATURES, ROW_DW, 0, stream>>>(v, (unsigned int*)d_ws);
        int grid = (B + ROWS_PER_BLOCK - 1) / ROWS_PER_BLOCK;
        ffm_pad<<<grid, THREADS, 0, stream>>>(x, w, bias, (const unsigned int*)d_ws, out, B);
    } else {
        int grid = (B + 15) / 16;
        ffm_fp32<<<grid, 256, 0, stream>>>(x, w, bias, v, out, B);
    }
}

// Round 5
// 39.199 us; speedup vs baseline: 2.1710x; 1.0762x over previous
//
#include <hip/hip_runtime.h>
#include <hip/hip_fp16.h>
#include <math.h>

#define N_DENSE 13
#define N_SPARSE 26
#define SPARSE_DIM 100
#define N_FIELD 39               // 13 + 26 real fields
#define N_FIELD_P 40             // padded (field 39 = zeros)
#define KDIM 16
#define N_FEATURES 2613          // 13 + 26*100
#define ROW_F 624                // real elements per feature row (39*16)
#define ROW_DW 320               // padded half2 per row (40 fields * 8 k-pairs)
#define THREADS 256
#define ROWS_PER_BLOCK 4         // one 64-lane wave per row

// ---------------- pre-pass: fp32 -> half2, padded to 40 fields --------------
// out[n][d]: d<312 -> half2(v[n*624+2d], v[n*624+2d+1]); d>=312 -> 0
__global__ __launch_bounds__(ROW_DW) void cvt_pad_f16(
    const float* __restrict__ v, __half2* __restrict__ o)
{
    int n = blockIdx.x;
    int d = threadIdx.x;
    __half2 r = __floats2half2_rn(0.f, 0.f);
    if (d < ROW_F / 2) {
        float2 f = *reinterpret_cast<const float2*>(v + (size_t)n * ROW_F + 2 * d);
        r = __floats2half2_rn(f.x, f.y);
    }
    o[(size_t)n * ROW_DW + d] = r;
}

// ---------------- main kernel: one wave per batch row -----------------------
// Row image: 320 half2; element d = (field f = d>>3, k-pair j = d&7).
// Lane l owns d = l + 64m (m=0..4): exactly 5 half2, all with j = l&7.
// Lane-group {l, l+8, ..., l+56} covers all 40 fields once -> reduce with
// xor {8,16,32}; then c summed over the 8 j-groups with xor {1,2,4}.
__global__ __launch_bounds__(THREADS, 8) void ffm_f16(
    const float* __restrict__ x,     // [B, 39]
    const float* __restrict__ w,     // [2613]
    const float* __restrict__ bias,  // [1]
    const __half2* __restrict__ vb,  // [2613, 320] padded half2 rows
    float* __restrict__ out,         // [B]
    int B)
{
    __shared__ __half2 ldsDense[N_DENSE * ROW_DW];   // 16640 B
    {
        const uint4* src = reinterpret_cast<const uint4*>(vb);
        uint4* dst = reinterpret_cast<uint4*>(ldsDense);
        for (int i = threadIdx.x; i < N_DENSE * ROW_DW / 4; i += THREADS)
            dst[i] = src[i];
    }
    __syncthreads();

    const int l = threadIdx.x & 63;
    // force wave-uniformity so x/w reads and gather bases scalarize (SGPR)
    const int wv = __builtin_amdgcn_readfirstlane((int)(threadIdx.x >> 6));
    const int row = blockIdx.x * ROWS_PER_BLOCK + wv;
    if (row >= B) return;

    const float* xr = x + row * (N_DENSE + N_SPARSE);

    __half2 acc[5];
#pragma unroll
    for (int m = 0; m < 5; ++m) acc[m] = __floats2half2_rn(0.f, 0.f);

    float lin = bias[0];

    // ---- dense features (LDS broadcast; fold linear part) ----
#pragma unroll
    for (int j = 0; j < N_DENSE; ++j) {
        float xv = xr[j];
        lin = fmaf(xv, w[j], lin);
        __half2 xh = __float2half2_rn(xv);
#pragma unroll
        for (int m = 0; m < 5; ++m)
            acc[m] = __hfma2(xh, ldsDense[j * ROW_DW + 64 * m + l], acc[m]);
    }

    // ---- sparse features: 2 features/iter, 10 loads in flight ----
#pragma unroll
    for (int s = 0; s < N_SPARSE; s += 2) {
        int i0 = N_DENSE + s * SPARSE_DIM + (int)xr[N_DENSE + s];
        int i1 = N_DENSE + (s + 1) * SPARSE_DIM + (int)xr[N_DENSE + s + 1];
        const __half2* b0 = vb + (size_t)i0 * ROW_DW + l;
        const __half2* b1 = vb + (size_t)i1 * ROW_DW + l;
        __half2 u0 = b0[0],   v0 = b1[0];
        __half2 u1 = b0[64],  v1 = b1[64];
        __half2 u2 = b0[128], v2 = b1[128];
        __half2 u3 = b0[192], v3 = b1[192];
        __half2 u4 = b0[256], v4 = b1[256];
        lin += w[i0] + w[i1];
        acc[0] = __hadd2(acc[0], u0); acc[0] = __hadd2(acc[0], v0);
        acc[1] = __hadd2(acc[1], u1); acc[1] = __hadd2(acc[1], v1);
        acc[2] = __hadd2(acc[2], u2); acc[2] = __hadd2(acc[2], v2);
        acc[3] = __hadd2(acc[3], u3); acc[3] = __hadd2(acc[3], v3);
        acc[4] = __hadd2(acc[4], u4); acc[4] = __hadd2(acc[4], v4);
    }

    // ---- reduction (f32) ----
    float sx = 0.f, sy = 0.f, qx = 0.f, qy = 0.f;
#pragma unroll
    for (int m = 0; m < 5; ++m) {
        float ax = __low2float(acc[m]);
        float ay = __high2float(acc[m]);
        sx += ax; sy += ay;
        qx = fmaf(ax, ax, qx);
        qy = fmaf(ay, ay, qy);
    }
#pragma unroll
    for (int mask = 8; mask <= 32; mask <<= 1) {
        sx += __shfl_xor(sx, mask);
        sy += __shfl_xor(sy, mask);
        qx += __shfl_xor(qx, mask);
        qy += __shfl_xor(qy, mask);
    }
    float c = (sx * sx - qx) + (sy * sy - qy);
    c += __shfl_xor(c, 1);
    c += __shfl_xor(c, 2);
    c += __shfl_xor(c, 4);

    float logit = lin + 0.5f * c;
    if (l == 0) out[row] = 1.f / (1.f + expf(-logit));
}

// ---------------- fp32 fallback (round-1 kernel, 16 lanes/row) --------------
#define ROW_Q (ROW_F / 4)
__global__ __launch_bounds__(256) void ffm_fp32(
    const float* __restrict__ x, const float* __restrict__ w,
    const float* __restrict__ bias, const float* __restrict__ v,
    float* __restrict__ out, int B)
{
    __shared__ float ldsDense[N_DENSE * ROW_F];
    const float4* v4 = reinterpret_cast<const float4*>(v);
    float4* lds4 = reinterpret_cast<float4*>(ldsDense);
    for (int i = threadIdx.x; i < N_DENSE * ROW_Q; i += 256) lds4[i] = v4[i];
    __syncthreads();

    const int g = threadIdx.x >> 4, l = threadIdx.x & 15;
    const int row = blockIdx.x * 16 + g;
    if (row >= B) return;
    const float* xr = x + row * (N_DENSE + N_SPARSE);

    float4 acc[10];
#pragma unroll
    for (int i = 0; i < 10; ++i) acc[i] = make_float4(0.f, 0.f, 0.f, 0.f);
#pragma unroll
    for (int j = 0; j < N_DENSE; ++j) {
        float xv = xr[j];
        const float4* b = lds4 + j * ROW_Q;
#pragma unroll
        for (int i = 0; i < 10; ++i)
            if (i < 9 || l < 12) {
                float4 t = b[l + 16 * i];
                acc[i].x += xv * t.x; acc[i].y += xv * t.y;
                acc[i].z += xv * t.z; acc[i].w += xv * t.w;
            }
    }
    int nidx[N_SPARSE];
#pragma unroll
    for (int s = 0; s < N_SPARSE; ++s)
        nidx[s] = N_DENSE + s * SPARSE_DIM + (int)xr[N_DENSE + s];
    for (int s = 0; s < N_SPARSE; ++s) {
        const float4* b = v4 + (size_t)nidx[s] * ROW_Q;
#pragma unroll
        for (int i = 0; i < 10; ++i)
            if (i < 9 || l < 12) {
                float4 t = b[l + 16 * i];
                acc[i].x += t.x; acc[i].y += t.y; acc[i].z += t.z; acc[i].w += t.w;
            }
    }
    float4 s4 = make_float4(0,0,0,0), q4 = make_float4(0,0,0,0);
#pragma unroll
    for (int i = 0; i < 10; ++i) {
        s4.x += acc[i].x; s4.y += acc[i].y; s4.z += acc[i].z; s4.w += acc[i].w;
        q4.x += acc[i].x*acc[i].x; q4.y += acc[i].y*acc[i].y;
        q4.z += acc[i].z*acc[i].z; q4.w += acc[i].w*acc[i].w;
    }
#pragma unroll
    for (int m = 4; m <= 8; m <<= 1) {
        s4.x += __shfl_xor(s4.x,m); s4.y += __shfl_xor(s4.y,m);
        s4.z += __shfl_xor(s4.z,m); s4.w += __shfl_xor(s4.w,m);
        q4.x += __shfl_xor(q4.x,m); q4.y += __shfl_xor(q4.y,m);
        q4.z += __shfl_xor(q4.z,m); q4.w += __shfl_xor(q4.w,m);
    }
    float c = (s4.x*s4.x - q4.x) + (s4.y*s4.y - q4.y) +
              (s4.z*s4.z - q4.z) + (s4.w*s4.w - q4.w);
    c += __shfl_xor(c,1); c += __shfl_xor(c,2);
    float lin = bias[0];
#pragma unroll
    for (int j = 0; j < N_DENSE; ++j) lin += xr[j]*w[j];
#pragma unroll
    for (int s = 0; s < N_SPARSE; ++s) lin += w[nidx[s]];
    float logit = lin + 0.5f*c;
    if (l == 0) out[row] = 1.f/(1.f+expf(-logit));
}

extern "C" void kernel_launch(void* const* d_in, const int* in_sizes, int n_in,
                              void* d_out, int out_size, void* d_ws, size_t ws_size,
                              hipStream_t stream) {
    const float* x    = (const float*)d_in[0];
    const float* w    = (const float*)d_in[1];
    const float* bias = (const float*)d_in[2];
    const float* v    = (const float*)d_in[3];
    float* out = (float*)d_out;

    int B = in_sizes[0] / (N_DENSE + N_SPARSE);
    size_t need = (size_t)N_FEATURES * ROW_DW * sizeof(__half2);  // 3,344,640 B

    if (ws_size >= need) {
        cvt_pad_f16<<<N_FEATURES, ROW_DW, 0, stream>>>(v, (__half2*)d_ws);
        int grid = (B + ROWS_PER_BLOCK - 1) / ROWS_PER_BLOCK;
        ffm_f16<<<grid, THREADS, 0, stream>>>(x, w, bias, (const __half2*)d_ws, out, B);
    } else {
        int grid = (B + 15) / 16;
        ffm_fp32<<<grid, 256, 0, stream>>>(x, w, bias, v, out, B);
    }
}